// Round 3
// baseline (2364.124 us; speedup 1.0000x reference)
//
#include <hip/hip_runtime.h>
#include <hip/hip_bf16.h>

// Attention decoder: B=512, T=64, C=512, H=512, NC=96, steps S=26.
// Strategy:
//   - Hproj = batch_H @ Wi hoisted (one big GEMM).
//   - Per step: GEMM1 (h @ [Wh | lstm_rec], N=2560) -> attention kernel ->
//               GEMM3 (ctx @ lstm_kernel[:512], N=2048) -> LSTM pointwise.
//   - onehot @ lstm_kernel == row gather of lstm_kernel[512+char] (no GEMM).
//   - All GEMMs: 3-pass bf16-split MFMA (Ahi*Bhi + Ahi*Blo + Alo*Bhi) for
//     ~fp32 precision at bf16-MFMA speed. A split on the fly from fp32;
//     B (weights) pre-transposed+split once per launch into ws.

#define NB 512
#define NT 64
#define NCH 512
#define NH 512
#define NCLS 96
#define NSTEP 26

typedef __bf16 bf16x8 __attribute__((ext_vector_type(8)));
typedef float f32x4 __attribute__((ext_vector_type(4)));

__device__ __forceinline__ float tanh_fast(float x) {
  float e = __expf(2.0f * x);
  return 1.0f - 2.0f / (e + 1.0f);
}
__device__ __forceinline__ float sigmoid_fast(float x) {
  return 1.0f / (1.0f + __expf(-x));
}

// ---------------------------------------------------------------------------
// Transpose + bf16-split weights: out[n][k] = split(src[k][n]), K = 512.
// Two-source variant handles the horizontal concat [Wh | lstm_rec].
// n >= Nvalid writes zeros (padding for Wgen N=96 -> 128).
// ---------------------------------------------------------------------------
__global__ __launch_bounds__(256) void transpose_split(
    const float* __restrict__ srcA, int ldA, int NA,
    const float* __restrict__ srcB, int ldB, int Nvalid,
    __hip_bfloat16* __restrict__ hi, __hip_bfloat16* __restrict__ lo) {
  __shared__ float tile[32][33];
  const int tx = threadIdx.x, ty = threadIdx.y;
  const int n0 = blockIdx.x * 32, k0 = blockIdx.y * 32;
#pragma unroll
  for (int i = 0; i < 4; ++i) {
    int k = k0 + ty + i * 8;
    int n = n0 + tx;
    float v = 0.f;
    if (n < NA) v = srcA[(size_t)k * ldA + n];
    else if (n < Nvalid) v = srcB[(size_t)k * ldB + (n - NA)];
    tile[tx][ty + i * 8] = v;
  }
  __syncthreads();
#pragma unroll
  for (int i = 0; i < 4; ++i) {
    int n = n0 + ty + i * 8;
    int k = k0 + tx;
    float v = tile[ty + i * 8][tx];
    __hip_bfloat16 h = __float2bfloat16(v);
    hi[(size_t)n * 512 + k] = h;
    lo[(size_t)n * 512 + k] = __float2bfloat16(v - __bfloat162float(h));
  }
}

// ---------------------------------------------------------------------------
// Split-precision GEMM: C[M][N] = A[M][512] (fp32) x B[512][N], where B is
// stored transposed+split as Bhi/Blo [N][512] bf16.
// Tile 128x64, 4 waves (wave tile 64x32), BK=64, mfma_f32_16x16x32_bf16.
// LDS chunk-XOR swizzle for conflict-free ds_read_b128.
// MODE 0: C[row*ldc+col] = acc.   MODE 1 (probs): remap row->(b,s), +bias,
//         col<96 only, writes [B,S,96].
// ---------------------------------------------------------------------------
template <int MODE>
__global__ __launch_bounds__(256) void gemm_split(
    const float* __restrict__ A,
    const __hip_bfloat16* __restrict__ Bhi,
    const __hip_bfloat16* __restrict__ Blo,
    float* __restrict__ Cout, int ldc, const float* __restrict__ bias) {
  __shared__ __align__(16) __hip_bfloat16 sAhi[128 * 64];
  __shared__ __align__(16) __hip_bfloat16 sAlo[128 * 64];
  __shared__ __align__(16) __hip_bfloat16 sBhi[64 * 64];
  __shared__ __align__(16) __hip_bfloat16 sBlo[64 * 64];

  const int tid = threadIdx.x;
  const int lane = tid & 63, wid = tid >> 6;
  const int mh = wid >> 1, nh = wid & 1;
  const int mBase = blockIdx.y * 128, nBase = blockIdx.x * 64;

  f32x4 acc[4][2];
#pragma unroll
  for (int fm = 0; fm < 4; ++fm)
#pragma unroll
    for (int fn = 0; fn < 2; ++fn) acc[fm][fn] = (f32x4){0.f, 0.f, 0.f, 0.f};

  for (int kt = 0; kt < 8; ++kt) {
    // Stage A (fp32 -> hi/lo bf16), 128 rows x 64 k. 1024 16B chunks.
#pragma unroll
    for (int i = 0; i < 4; ++i) {
      int cid = tid + i * 256;
      int row = cid >> 3, ch = cid & 7;
      const float* src = A + (size_t)(mBase + row) * 512 + kt * 64 + ch * 8;
      float4 v0 = *(const float4*)src;
      float4 v1 = *(const float4*)(src + 4);
      float vv[8] = {v0.x, v0.y, v0.z, v0.w, v1.x, v1.y, v1.z, v1.w};
      union { int4 q; __hip_bfloat16 h[8]; } uh, ul;
#pragma unroll
      for (int j = 0; j < 8; ++j) {
        __hip_bfloat16 hb = __float2bfloat16(vv[j]);
        uh.h[j] = hb;
        ul.h[j] = __float2bfloat16(vv[j] - __bfloat162float(hb));
      }
      int swz = ch ^ (row & 7);
      *(int4*)&sAhi[row * 64 + swz * 8] = uh.q;
      *(int4*)&sAlo[row * 64 + swz * 8] = ul.q;
    }
    // Stage B (already split), 64 n-rows x 64 k. 512 chunks each.
#pragma unroll
    for (int i = 0; i < 2; ++i) {
      int cid = tid + i * 256;
      int row = cid >> 3, ch = cid & 7;
      int swz = ch ^ (row & 7);
      size_t goff = (size_t)(nBase + row) * 512 + kt * 64 + ch * 8;
      *(int4*)&sBhi[row * 64 + swz * 8] = *(const int4*)&Bhi[goff];
      *(int4*)&sBlo[row * 64 + swz * 8] = *(const int4*)&Blo[goff];
    }
    __syncthreads();

#pragma unroll
    for (int kk = 0; kk < 2; ++kk) {
      bf16x8 ahi[4], alo[4], bhi[2], blo[2];
#pragma unroll
      for (int fm = 0; fm < 4; ++fm) {
        int row = mh * 64 + fm * 16 + (lane & 15);
        int ch = kk * 4 + (lane >> 4);
        int swz = ch ^ (row & 7);
        ahi[fm] = *(const bf16x8*)&sAhi[row * 64 + swz * 8];
        alo[fm] = *(const bf16x8*)&sAlo[row * 64 + swz * 8];
      }
#pragma unroll
      for (int fn = 0; fn < 2; ++fn) {
        int row = nh * 32 + fn * 16 + (lane & 15);
        int ch = kk * 4 + (lane >> 4);
        int swz = ch ^ (row & 7);
        bhi[fn] = *(const bf16x8*)&sBhi[row * 64 + swz * 8];
        blo[fn] = *(const bf16x8*)&sBlo[row * 64 + swz * 8];
      }
#pragma unroll
      for (int fm = 0; fm < 4; ++fm)
#pragma unroll
        for (int fn = 0; fn < 2; ++fn) {
          acc[fm][fn] = __builtin_amdgcn_mfma_f32_16x16x32_bf16(ahi[fm], bhi[fn], acc[fm][fn], 0, 0, 0);
          acc[fm][fn] = __builtin_amdgcn_mfma_f32_16x16x32_bf16(ahi[fm], blo[fn], acc[fm][fn], 0, 0, 0);
          acc[fm][fn] = __builtin_amdgcn_mfma_f32_16x16x32_bf16(alo[fm], bhi[fn], acc[fm][fn], 0, 0, 0);
        }
    }
    __syncthreads();
  }

  // Epilogue. C/D layout (m89-verified): col = lane&15, row = (lane>>4)*4+r.
#pragma unroll
  for (int fm = 0; fm < 4; ++fm)
#pragma unroll
    for (int fn = 0; fn < 2; ++fn)
#pragma unroll
      for (int r = 0; r < 4; ++r) {
        int row = mBase + mh * 64 + fm * 16 + (lane >> 4) * 4 + r;
        int col = nBase + nh * 32 + fn * 16 + (lane & 15);
        float v = acc[fm][fn][r];
        if (MODE == 0) {
          Cout[(size_t)row * ldc + col] = v;
        } else {
          int bb = row & 511, ss = row >> 9;   // A row = s*512 + b
          if (col < NCLS)
            Cout[((size_t)bb * NSTEP + ss) * NCLS + col] = v + bias[col];
        }
      }
}

// ---------------------------------------------------------------------------
// Attention: e = tanh(Hproj + q) @ Ws ; alpha = softmax_T(e) ;
// ctx = sum_t alpha_t * batch_H[b,t,:]. One block per batch row, 512 threads.
// ---------------------------------------------------------------------------
__global__ __launch_bounds__(512) void attn_kernel(
    const float* __restrict__ qh, const float* __restrict__ bh,
    const float* __restrict__ Ws, const float* __restrict__ Hproj,
    const float* __restrict__ batchH, float* __restrict__ ctx) {
  const int b = blockIdx.x;
  const int tid = threadIdx.x;
  const int lane = tid & 63, w = tid >> 6;  // 8 waves

  __shared__ float qs[512];
  __shared__ float wss[512];
  __shared__ float es[64];
  __shared__ float als[64];

  if (tid < 512) {
    qs[tid] = qh[(size_t)b * 2560 + tid] + bh[tid];
    wss[tid] = Ws[tid];
  }
  __syncthreads();

  // Per-lane q/Ws registers: the lane's h-slice (h = lane*8 + j) is the same
  // for every t, so read LDS once (amortizes the strided-LDS conflict).
  float qv[8], wv[8];
#pragma unroll
  for (int j = 0; j < 8; ++j) {
    qv[j] = qs[lane * 8 + j];
    wv[j] = wss[lane * 8 + j];
  }

  const float* Hp = Hproj + (size_t)b * NT * NH;
#pragma unroll
  for (int i = 0; i < 8; ++i) {
    int t = w * 8 + i;
    const float* row = Hp + (size_t)t * NH + lane * 8;
    float4 a = *(const float4*)row;
    float4 c = *(const float4*)(row + 4);
    float sum = wv[0] * tanh_fast(a.x + qv[0]) + wv[1] * tanh_fast(a.y + qv[1]) +
                wv[2] * tanh_fast(a.z + qv[2]) + wv[3] * tanh_fast(a.w + qv[3]) +
                wv[4] * tanh_fast(c.x + qv[4]) + wv[5] * tanh_fast(c.y + qv[5]) +
                wv[6] * tanh_fast(c.z + qv[6]) + wv[7] * tanh_fast(c.w + qv[7]);
#pragma unroll
    for (int off = 32; off; off >>= 1) sum += __shfl_xor(sum, off);
    if (lane == 0) es[t] = sum;
  }
  __syncthreads();

  if (w == 0) {  // softmax over 64 encoder steps, one wave
    float e = es[lane];
    float m = e;
#pragma unroll
    for (int off = 32; off; off >>= 1) m = fmaxf(m, __shfl_xor(m, off));
    float p = __expf(e - m);
    float s = p;
#pragma unroll
    for (int off = 32; off; off >>= 1) s += __shfl_xor(s, off);
    als[lane] = p / s;
  }
  __syncthreads();

  // context: each thread owns one channel c0 = tid
  float acc = 0.f;
  const float* Bp = batchH + (size_t)b * NT * NCH + tid;
#pragma unroll 4
  for (int t = 0; t < NT; ++t) acc += als[t] * Bp[(size_t)t * NCH];
  ctx[(size_t)b * NCH + tid] = acc;
}

// ---------------------------------------------------------------------------
// LSTM pointwise: z = ctxGEMM + hrec + bias + lstm_kernel[512+char] row;
// gates i,f,g,o -> c,h. Writes h into hs slot s+1.
// ---------------------------------------------------------------------------
__global__ __launch_bounds__(256) void lstm_update(
    const float* __restrict__ z, const float* __restrict__ qh,
    const float* __restrict__ lstm_bias, const float* __restrict__ lstm_kernel,
    const int* __restrict__ text, int s,
    float* __restrict__ cstate, float* __restrict__ hs) {
  const int gid = blockIdx.x * 256 + threadIdx.x;  // 0..262143
  const int b = gid >> 9, j = gid & 511;
  const int ch = text[b * NSTEP + s];
  const float* crow = lstm_kernel + (size_t)(512 + ch) * 2048;
  float g4[4];
#pragma unroll
  for (int g = 0; g < 4; ++g) {
    int col = g * 512 + j;
    g4[g] = z[(size_t)b * 2048 + col] + qh[(size_t)b * 2560 + 512 + col] +
            lstm_bias[col] + crow[col];
  }
  float iv = sigmoid_fast(g4[0]);
  float fv = sigmoid_fast(g4[1]);
  float gv = tanh_fast(g4[2]);
  float ov = sigmoid_fast(g4[3]);
  float c = fv * cstate[gid] + iv * gv;
  cstate[gid] = c;
  hs[(size_t)(s + 1) * (NB * NH) + gid] = ov * tanh_fast(c);
}

// ---------------------------------------------------------------------------
extern "C" void kernel_launch(void* const* d_in, const int* in_sizes, int n_in,
                              void* d_out, int out_size, void* d_ws, size_t ws_size,
                              hipStream_t stream) {
  (void)in_sizes; (void)n_in; (void)out_size; (void)ws_size;
  const float* batch_H = (const float*)d_in[0];
  const int* text = (const int*)d_in[1];
  const float* Wi = (const float*)d_in[3];
  const float* Wh = (const float*)d_in[4];
  const float* bh = (const float*)d_in[5];
  const float* Ws = (const float*)d_in[6];
  const float* lstm_kernel = (const float*)d_in[7];
  const float* lstm_rec = (const float*)d_in[8];
  const float* lstm_bias = (const float*)d_in[9];
  const float* Wgen = (const float*)d_in[10];
  const float* bgen = (const float*)d_in[11];
  float* out = (float*)d_out;

  char* w = (char*)d_ws;
  auto alloc = [&](size_t bytes) {
    char* p = w;
    w += (bytes + 255) & ~(size_t)255;
    return p;
  };
  float* Hproj = (float*)alloc(32768ull * 512 * 4);
  __hip_bfloat16* WiT_hi = (__hip_bfloat16*)alloc(512ull * 512 * 2);
  __hip_bfloat16* WiT_lo = (__hip_bfloat16*)alloc(512ull * 512 * 2);
  __hip_bfloat16* W2T_hi = (__hip_bfloat16*)alloc(2560ull * 512 * 2);
  __hip_bfloat16* W2T_lo = (__hip_bfloat16*)alloc(2560ull * 512 * 2);
  __hip_bfloat16* K1T_hi = (__hip_bfloat16*)alloc(2048ull * 512 * 2);
  __hip_bfloat16* K1T_lo = (__hip_bfloat16*)alloc(2048ull * 512 * 2);
  __hip_bfloat16* WgT_hi = (__hip_bfloat16*)alloc(128ull * 512 * 2);
  __hip_bfloat16* WgT_lo = (__hip_bfloat16*)alloc(128ull * 512 * 2);
  float* qhbuf = (float*)alloc(512ull * 2560 * 4);
  float* zbuf = (float*)alloc(512ull * 2048 * 4);
  float* ctx = (float*)alloc(512ull * 512 * 4);
  float* hs = (float*)alloc(27ull * 512 * 512 * 4);  // slot 0 = zeros (h_{-1})
  float* cstate = (float*)alloc(512ull * 512 * 4);

  dim3 tb(32, 8, 1);
  // Weight transpose+split (once per launch; graph-safe).
  transpose_split<<<dim3(16, 16), tb, 0, stream>>>(Wi, 512, 512, Wi, 512, 512, WiT_hi, WiT_lo);
  transpose_split<<<dim3(80, 16), tb, 0, stream>>>(Wh, 512, 512, lstm_rec, 2048, 2560, W2T_hi, W2T_lo);
  transpose_split<<<dim3(64, 16), tb, 0, stream>>>(lstm_kernel, 2048, 2048, lstm_kernel, 2048, 2048, K1T_hi, K1T_lo);
  transpose_split<<<dim3(4, 16), tb, 0, stream>>>(Wgen, 96, 96, Wgen, 96, 96, WgT_hi, WgT_lo);

  hipMemsetAsync(hs, 0, (size_t)512 * 512 * 4, stream);      // h_{-1} = 0
  hipMemsetAsync(cstate, 0, (size_t)512 * 512 * 4, stream);  // c_{-1} = 0

  // Hproj = batch_H @ Wi : M=32768, N=512
  gemm_split<0><<<dim3(8, 256), 256, 0, stream>>>(batch_H, WiT_hi, WiT_lo, Hproj, 512, nullptr);

  for (int s = 0; s < NSTEP; ++s) {
    const float* hptr = hs + (size_t)s * (NB * NH);
    // q | hrec = h @ [Wh | lstm_rec] : M=512, N=2560
    gemm_split<0><<<dim3(40, 4), 256, 0, stream>>>(hptr, W2T_hi, W2T_lo, qhbuf, 2560, nullptr);
    attn_kernel<<<dim3(NB), 512, 0, stream>>>(qhbuf, bh, Ws, Hproj, batch_H, ctx);
    // z = ctx @ lstm_kernel[:512] : M=512, N=2048
    gemm_split<0><<<dim3(32, 4), 256, 0, stream>>>(ctx, K1T_hi, K1T_lo, zbuf, 2048, nullptr);
    lstm_update<<<dim3(1024), 256, 0, stream>>>(zbuf, qhbuf, lstm_bias, lstm_kernel, text, s, cstate, hs);
  }

  // probs = hs @ Wgen + bgen : A rows = hs slots 1..26 (M=13312), N=128 (96 valid)
  gemm_split<1><<<dim3(2, 104), 256, 0, stream>>>(hs + (size_t)NB * NH, WgT_hi, WgT_lo, out, NCLS, bgen);
}

// Round 4
// 2341.999 us; speedup vs baseline: 1.0094x; 1.0094x over previous
//
#include <hip/hip_runtime.h>
#include <hip/hip_bf16.h>

// Attention decoder: B=512, T=64, C=512, H=512, NC=96, steps S=26.
//   - Hproj GEMM (XCD-swizzled) writes Hproj as bf16 + side-writes bf16
//     copy of batch_H during A staging (no extra global reads).
//   - Per step: gemm1 (h @ [Wh|lstm_rec]) -> attn (bf16 reads) ->
//               gemm3_lstm (ctx GEMM + fused LSTM pointwise).
//   - GEMMs: 3-pass bf16-split MFMA (~fp32 precision).

#define NB 512
#define NT 64
#define NCH 512
#define NH 512
#define NCLS 96
#define NSTEP 26

typedef __bf16 bf16x8 __attribute__((ext_vector_type(8)));
typedef float f32x4 __attribute__((ext_vector_type(4)));

__device__ __forceinline__ float tanh_fast(float x) {
  float e = __expf(2.0f * x);
  return 1.0f - 2.0f / (e + 1.0f);
}
__device__ __forceinline__ float sigmoid_fast(float x) {
  return 1.0f / (1.0f + __expf(-x));
}
__device__ __forceinline__ float bflo(unsigned u) {
  union { unsigned i; float f; } c; c.i = u << 16; return c.f;
}
__device__ __forceinline__ float bfhi(unsigned u) {
  union { unsigned i; float f; } c; c.i = u & 0xffff0000u; return c.f;
}

// ---------------------------------------------------------------------------
// Transpose + bf16-split weights: out[n][k] = split(src[k][n]), K = 512.
// ---------------------------------------------------------------------------
__global__ __launch_bounds__(256) void transpose_split(
    const float* __restrict__ srcA, int ldA, int NA,
    const float* __restrict__ srcB, int ldB, int Nvalid,
    __hip_bfloat16* __restrict__ hi, __hip_bfloat16* __restrict__ lo) {
  __shared__ float tile[32][33];
  const int tx = threadIdx.x, ty = threadIdx.y;
  const int n0 = blockIdx.x * 32, k0 = blockIdx.y * 32;
#pragma unroll
  for (int i = 0; i < 4; ++i) {
    int k = k0 + ty + i * 8;
    int n = n0 + tx;
    float v = 0.f;
    if (n < NA) v = srcA[(size_t)k * ldA + n];
    else if (n < Nvalid) v = srcB[(size_t)k * ldB + (n - NA)];
    tile[tx][ty + i * 8] = v;
  }
  __syncthreads();
#pragma unroll
  for (int i = 0; i < 4; ++i) {
    int n = n0 + ty + i * 8;
    int k = k0 + tx;
    float v = tile[ty + i * 8][tx];
    __hip_bfloat16 h = __float2bfloat16(v);
    hi[(size_t)n * 512 + k] = h;
    lo[(size_t)n * 512 + k] = __float2bfloat16(v - __bfloat162float(h));
  }
}

// ---------------------------------------------------------------------------
// Split-precision GEMM, tile 128x64, 4 waves, BK=64, mfma 16x16x32 bf16.
// MODE 0: fp32 C write. MODE 1: probs epilogue (+bias, col<96, [B,S,96]).
// MODE 2: Hproj — XCD-bijective swizzle (grid 8x256), bf16 C write to c16,
//         and x==0 blocks side-write bf16 A (batch_H) to bh16 while staging.
// ---------------------------------------------------------------------------
template <int MODE>
__global__ __launch_bounds__(256) void gemm_split(
    const float* __restrict__ A,
    const __hip_bfloat16* __restrict__ Bhi,
    const __hip_bfloat16* __restrict__ Blo,
    float* __restrict__ Cout, int ldc, const float* __restrict__ bias,
    __hip_bfloat16* __restrict__ c16, __hip_bfloat16* __restrict__ bh16) {
  __shared__ __align__(16) __hip_bfloat16 sAhi[128 * 64];
  __shared__ __align__(16) __hip_bfloat16 sAlo[128 * 64];
  __shared__ __align__(16) __hip_bfloat16 sBhi[64 * 64];
  __shared__ __align__(16) __hip_bfloat16 sBlo[64 * 64];

  const int tid = threadIdx.x;
  const int lane = tid & 63, wid = tid >> 6;
  const int mh = wid >> 1, nh = wid & 1;

  int bx = blockIdx.x, by = blockIdx.y;
  if (MODE == 2) {
    // grid (8,256): co-locate the 8 x-blocks sharing an A row-panel on one
    // XCD (assign each XCD 32 consecutive panels). Bijective remap.
    int lid = by * 8 + bx;
    int xcd = lid & 7, k = lid >> 3;   // k in [0,256)
    by = xcd * 32 + (k >> 3);
    bx = k & 7;
  }
  const int mBase = by * 128, nBase = bx * 64;

  f32x4 acc[4][2];
#pragma unroll
  for (int fm = 0; fm < 4; ++fm)
#pragma unroll
    for (int fn = 0; fn < 2; ++fn) acc[fm][fn] = (f32x4){0.f, 0.f, 0.f, 0.f};

  for (int kt = 0; kt < 8; ++kt) {
#pragma unroll
    for (int i = 0; i < 4; ++i) {
      int cid = tid + i * 256;
      int row = cid >> 3, ch = cid & 7;
      const float* src = A + (size_t)(mBase + row) * 512 + kt * 64 + ch * 8;
      float4 v0 = *(const float4*)src;
      float4 v1 = *(const float4*)(src + 4);
      float vv[8] = {v0.x, v0.y, v0.z, v0.w, v1.x, v1.y, v1.z, v1.w};
      union { int4 q; __hip_bfloat16 h[8]; } uh, ul;
#pragma unroll
      for (int j = 0; j < 8; ++j) {
        __hip_bfloat16 hb = __float2bfloat16(vv[j]);
        uh.h[j] = hb;
        ul.h[j] = __float2bfloat16(vv[j] - __bfloat162float(hb));
      }
      int swz = ch ^ (row & 7);
      *(int4*)&sAhi[row * 64 + swz * 8] = uh.q;
      *(int4*)&sAlo[row * 64 + swz * 8] = ul.q;
      if (MODE == 2 && bx == 0)  // bf16 copy of batch_H, written once per panel
        *(int4*)&bh16[(size_t)(mBase + row) * 512 + kt * 64 + ch * 8] = uh.q;
    }
#pragma unroll
    for (int i = 0; i < 2; ++i) {
      int cid = tid + i * 256;
      int row = cid >> 3, ch = cid & 7;
      int swz = ch ^ (row & 7);
      size_t goff = (size_t)(nBase + row) * 512 + kt * 64 + ch * 8;
      *(int4*)&sBhi[row * 64 + swz * 8] = *(const int4*)&Bhi[goff];
      *(int4*)&sBlo[row * 64 + swz * 8] = *(const int4*)&Blo[goff];
    }
    __syncthreads();

#pragma unroll
    for (int kk = 0; kk < 2; ++kk) {
      bf16x8 ahi[4], alo[4], bhi[2], blo[2];
#pragma unroll
      for (int fm = 0; fm < 4; ++fm) {
        int row = mh * 64 + fm * 16 + (lane & 15);
        int ch = kk * 4 + (lane >> 4);
        int swz = ch ^ (row & 7);
        ahi[fm] = *(const bf16x8*)&sAhi[row * 64 + swz * 8];
        alo[fm] = *(const bf16x8*)&sAlo[row * 64 + swz * 8];
      }
#pragma unroll
      for (int fn = 0; fn < 2; ++fn) {
        int row = nh * 32 + fn * 16 + (lane & 15);
        int ch = kk * 4 + (lane >> 4);
        int swz = ch ^ (row & 7);
        bhi[fn] = *(const bf16x8*)&sBhi[row * 64 + swz * 8];
        blo[fn] = *(const bf16x8*)&sBlo[row * 64 + swz * 8];
      }
#pragma unroll
      for (int fm = 0; fm < 4; ++fm)
#pragma unroll
        for (int fn = 0; fn < 2; ++fn) {
          acc[fm][fn] = __builtin_amdgcn_mfma_f32_16x16x32_bf16(ahi[fm], bhi[fn], acc[fm][fn], 0, 0, 0);
          acc[fm][fn] = __builtin_amdgcn_mfma_f32_16x16x32_bf16(ahi[fm], blo[fn], acc[fm][fn], 0, 0, 0);
          acc[fm][fn] = __builtin_amdgcn_mfma_f32_16x16x32_bf16(alo[fm], bhi[fn], acc[fm][fn], 0, 0, 0);
        }
    }
    __syncthreads();
  }

  // Epilogue. C/D layout: col = lane&15, row = (lane>>4)*4+r.
#pragma unroll
  for (int fm = 0; fm < 4; ++fm)
#pragma unroll
    for (int fn = 0; fn < 2; ++fn)
#pragma unroll
      for (int r = 0; r < 4; ++r) {
        int row = mBase + mh * 64 + fm * 16 + (lane >> 4) * 4 + r;
        int col = nBase + nh * 32 + fn * 16 + (lane & 15);
        float v = acc[fm][fn][r];
        if (MODE == 0) {
          Cout[(size_t)row * ldc + col] = v;
        } else if (MODE == 2) {
          c16[(size_t)row * 512 + col] = __float2bfloat16(v);
        } else {
          int bb = row & 511, ss = row >> 9;   // A row = s*512 + b
          if (col < NCLS)
            Cout[((size_t)bb * NSTEP + ss) * NCLS + col] = v + bias[col];
        }
      }
}

// ---------------------------------------------------------------------------
// Attention (bf16 operands): e = tanh(Hp16 + q) @ Ws; alpha = softmax_T(e);
// ctx = sum_t alpha_t * bH16[b,t,:]. One block per batch row, 512 threads.
// ---------------------------------------------------------------------------
__global__ __launch_bounds__(512) void attn_kernel(
    const float* __restrict__ qh, const float* __restrict__ bh,
    const float* __restrict__ Ws, const __hip_bfloat16* __restrict__ Hp16,
    const __hip_bfloat16* __restrict__ bH16, float* __restrict__ ctx) {
  const int b = blockIdx.x;
  const int tid = threadIdx.x;
  const int lane = tid & 63, w = tid >> 6;  // 8 waves

  __shared__ float qs[512];
  __shared__ float wss[512];
  __shared__ float es[64];
  __shared__ float als[64];
  __shared__ float2 cpart[2][256];

  qs[tid] = qh[(size_t)b * 2560 + tid] + bh[tid];
  wss[tid] = Ws[tid];
  __syncthreads();

  float qv[8], wv[8];
#pragma unroll
  for (int j = 0; j < 8; ++j) {
    qv[j] = qs[lane * 8 + j];
    wv[j] = wss[lane * 8 + j];
  }

  const __hip_bfloat16* Hp = Hp16 + (size_t)b * NT * NH;
#pragma unroll
  for (int i = 0; i < 8; ++i) {
    int t = w * 8 + i;
    uint4 p = *(const uint4*)(Hp + (size_t)t * NH + lane * 8);
    float sum = wv[0] * tanh_fast(bflo(p.x) + qv[0]) + wv[1] * tanh_fast(bfhi(p.x) + qv[1]) +
                wv[2] * tanh_fast(bflo(p.y) + qv[2]) + wv[3] * tanh_fast(bfhi(p.y) + qv[3]) +
                wv[4] * tanh_fast(bflo(p.z) + qv[4]) + wv[5] * tanh_fast(bfhi(p.z) + qv[5]) +
                wv[6] * tanh_fast(bflo(p.w) + qv[6]) + wv[7] * tanh_fast(bfhi(p.w) + qv[7]);
#pragma unroll
    for (int off = 32; off; off >>= 1) sum += __shfl_xor(sum, off);
    if (lane == 0) es[t] = sum;
  }
  __syncthreads();

  if (w == 0) {  // softmax over 64 encoder steps
    float e = es[lane];
    float m = e;
#pragma unroll
    for (int off = 32; off; off >>= 1) m = fmaxf(m, __shfl_xor(m, off));
    float p = __expf(e - m);
    float s = p;
#pragma unroll
    for (int off = 32; off; off >>= 1) s += __shfl_xor(s, off);
    als[lane] = p / s;
  }
  __syncthreads();

  // ctx: 256 channel-pairs x 2 t-halves
  const int c2 = tid & 255, hh = tid >> 8;
  const __hip_bfloat16* Bp = bH16 + (size_t)b * NT * NCH;
  float sx = 0.f, sy = 0.f;
  for (int t = hh * 32; t < hh * 32 + 32; ++t) {
    unsigned u = *(const unsigned*)(Bp + (size_t)t * NCH + c2 * 2);
    float a = als[t];
    sx += a * bflo(u);
    sy += a * bfhi(u);
  }
  cpart[hh][c2] = make_float2(sx, sy);
  __syncthreads();
  if (tid < 256) {
    float2 p0 = cpart[0][tid], p1 = cpart[1][tid];
    *(float2*)&ctx[(size_t)b * NCH + tid * 2] = make_float2(p0.x + p1.x, p0.y + p1.y);
  }
}

// ---------------------------------------------------------------------------
// ctx GEMM + fused LSTM. Block: 64 rows x 32 j-cols (=> 128 strided z-cols,
// all 4 gates). 4 waves, wave tile 32x64(local). z exchanged via LDS, then
// pointwise LSTM epilogue writes c and h (hs slot s+1).
// ---------------------------------------------------------------------------
__global__ __launch_bounds__(256) void gemm3_lstm(
    const float* __restrict__ ctxA,
    const __hip_bfloat16* __restrict__ Bhi,   // K1T [2048][512]
    const __hip_bfloat16* __restrict__ Blo,
    const float* __restrict__ qh,             // hrec at col offset 512
    const float* __restrict__ lstm_bias,
    const float* __restrict__ lstm_kernel,
    const int* __restrict__ text, int s,
    float* __restrict__ cstate, float* __restrict__ hs) {
  __shared__ __align__(16) char smraw[49152];
  __hip_bfloat16* sAhi = (__hip_bfloat16*)smraw;        // 8 KB
  __hip_bfloat16* sAlo = sAhi + 64 * 64;                // 8 KB
  __hip_bfloat16* sBh = sAlo + 64 * 64;                 // 16 KB
  __hip_bfloat16* sBl = sBh + 128 * 64;                 // 16 KB
  float* zl = (float*)smraw;                            // 32 KB, reused

  const int tid = threadIdx.x;
  const int lane = tid & 63, wid = tid >> 6;
  const int wm = wid >> 1, wl = wid & 1;
  const int mBase = blockIdx.y * 64;   // batch rows
  const int j0 = blockIdx.x * 32;      // j within gate

  f32x4 acc[2][4];
#pragma unroll
  for (int fm = 0; fm < 2; ++fm)
#pragma unroll
    for (int fl = 0; fl < 4; ++fl) acc[fm][fl] = (f32x4){0.f, 0.f, 0.f, 0.f};

  for (int kt = 0; kt < 8; ++kt) {
    // stage A (ctx fp32 -> hi/lo): 64 rows x 8 chunks
#pragma unroll
    for (int i = 0; i < 2; ++i) {
      int cid = tid + i * 256;
      int row = cid >> 3, ch = cid & 7;
      const float* src = ctxA + (size_t)(mBase + row) * 512 + kt * 64 + ch * 8;
      float4 v0 = *(const float4*)src;
      float4 v1 = *(const float4*)(src + 4);
      float vv[8] = {v0.x, v0.y, v0.z, v0.w, v1.x, v1.y, v1.z, v1.w};
      union { int4 q; __hip_bfloat16 h[8]; } uh, ul;
#pragma unroll
      for (int j = 0; j < 8; ++j) {
        __hip_bfloat16 hb = __float2bfloat16(vv[j]);
        uh.h[j] = hb;
        ul.h[j] = __float2bfloat16(vv[j] - __bfloat162float(hb));
      }
      int swz = ch ^ (row & 7);
      *(int4*)&sAhi[row * 64 + swz * 8] = uh.q;
      *(int4*)&sAlo[row * 64 + swz * 8] = ul.q;
    }
    // stage B: 128 local rows (gate g, col j0+jj) x 8 chunks
#pragma unroll
    for (int i = 0; i < 4; ++i) {
      int cid = tid + i * 256;
      int lr = cid >> 3, ch = cid & 7;
      int g = lr >> 5, jj = lr & 31;
      size_t goff = (size_t)(g * 512 + j0 + jj) * 512 + kt * 64 + ch * 8;
      int swz = ch ^ (lr & 7);
      *(int4*)&sBh[lr * 64 + swz * 8] = *(const int4*)&Bhi[goff];
      *(int4*)&sBl[lr * 64 + swz * 8] = *(const int4*)&Blo[goff];
    }
    __syncthreads();

#pragma unroll
    for (int kk = 0; kk < 2; ++kk) {
      bf16x8 ahi[2], alo[2], bhi[4], blo[4];
#pragma unroll
      for (int fm = 0; fm < 2; ++fm) {
        int row = wm * 32 + fm * 16 + (lane & 15);
        int ch = kk * 4 + (lane >> 4);
        int swz = ch ^ (row & 7);
        ahi[fm] = *(const bf16x8*)&sAhi[row * 64 + swz * 8];
        alo[fm] = *(const bf16x8*)&sAlo[row * 64 + swz * 8];
      }
#pragma unroll
      for (int fl = 0; fl < 4; ++fl) {
        int lr = wl * 64 + fl * 16 + (lane & 15);
        int ch = kk * 4 + (lane >> 4);
        int swz = ch ^ (lr & 7);
        bhi[fl] = *(const bf16x8*)&sBh[lr * 64 + swz * 8];
        blo[fl] = *(const bf16x8*)&sBl[lr * 64 + swz * 8];
      }
#pragma unroll
      for (int fm = 0; fm < 2; ++fm)
#pragma unroll
        for (int fl = 0; fl < 4; ++fl) {
          acc[fm][fl] = __builtin_amdgcn_mfma_f32_16x16x32_bf16(ahi[fm], bhi[fl], acc[fm][fl], 0, 0, 0);
          acc[fm][fl] = __builtin_amdgcn_mfma_f32_16x16x32_bf16(ahi[fm], blo[fl], acc[fm][fl], 0, 0, 0);
          acc[fm][fl] = __builtin_amdgcn_mfma_f32_16x16x32_bf16(alo[fm], bhi[fl], acc[fm][fl], 0, 0, 0);
        }
    }
    __syncthreads();
  }

  // z -> LDS (aliases staging buffers; safe after the trailing barrier)
#pragma unroll
  for (int fm = 0; fm < 2; ++fm)
#pragma unroll
    for (int fl = 0; fl < 4; ++fl)
#pragma unroll
      for (int r = 0; r < 4; ++r) {
        int row = wm * 32 + fm * 16 + (lane >> 4) * 4 + r;
        int lr = wl * 64 + fl * 16 + (lane & 15);
        zl[row * 128 + lr] = acc[fm][fl][r];
      }
  __syncthreads();

  // pointwise LSTM: 64 rows x 32 j = 2048 outputs
  for (int p = tid; p < 64 * 32; p += 256) {
    int row = p >> 5, j = p & 31;
    int b = mBase + row, jc = j0 + j;
    int chr = text[b * NSTEP + s];
    const float* crow = lstm_kernel + (size_t)(512 + chr) * 2048;
    const float* hrec = qh + (size_t)b * 2560 + 512;
    float g4[4];
#pragma unroll
    for (int g = 0; g < 4; ++g) {
      int col = g * 512 + jc;
      g4[g] = zl[row * 128 + g * 32 + j] + hrec[col] + lstm_bias[col] + crow[col];
    }
    float iv = sigmoid_fast(g4[0]);
    float fv = sigmoid_fast(g4[1]);
    float gv = tanh_fast(g4[2]);
    float ov = sigmoid_fast(g4[3]);
    size_t gi = (size_t)b * 512 + jc;
    float c = fv * cstate[gi] + iv * gv;
    cstate[gi] = c;
    hs[(size_t)(s + 1) * (NB * NH) + gi] = ov * tanh_fast(c);
  }
}

// ---------------------------------------------------------------------------
extern "C" void kernel_launch(void* const* d_in, const int* in_sizes, int n_in,
                              void* d_out, int out_size, void* d_ws, size_t ws_size,
                              hipStream_t stream) {
  (void)in_sizes; (void)n_in; (void)out_size; (void)ws_size;
  const float* batch_H = (const float*)d_in[0];
  const int* text = (const int*)d_in[1];
  const float* Wi = (const float*)d_in[3];
  const float* Wh = (const float*)d_in[4];
  const float* bh = (const float*)d_in[5];
  const float* Ws = (const float*)d_in[6];
  const float* lstm_kernel = (const float*)d_in[7];
  const float* lstm_rec = (const float*)d_in[8];
  const float* lstm_bias = (const float*)d_in[9];
  const float* Wgen = (const float*)d_in[10];
  const float* bgen = (const float*)d_in[11];
  float* out = (float*)d_out;

  char* w = (char*)d_ws;
  auto alloc = [&](size_t bytes) {
    char* p = w;
    w += (bytes + 255) & ~(size_t)255;
    return p;
  };
  __hip_bfloat16* Hp16 = (__hip_bfloat16*)alloc(32768ull * 512 * 2);
  __hip_bfloat16* bH16 = (__hip_bfloat16*)alloc(32768ull * 512 * 2);
  __hip_bfloat16* WiT_hi = (__hip_bfloat16*)alloc(512ull * 512 * 2);
  __hip_bfloat16* WiT_lo = (__hip_bfloat16*)alloc(512ull * 512 * 2);
  __hip_bfloat16* W2T_hi = (__hip_bfloat16*)alloc(2560ull * 512 * 2);
  __hip_bfloat16* W2T_lo = (__hip_bfloat16*)alloc(2560ull * 512 * 2);
  __hip_bfloat16* K1T_hi = (__hip_bfloat16*)alloc(2048ull * 512 * 2);
  __hip_bfloat16* K1T_lo = (__hip_bfloat16*)alloc(2048ull * 512 * 2);
  __hip_bfloat16* WgT_hi = (__hip_bfloat16*)alloc(128ull * 512 * 2);
  __hip_bfloat16* WgT_lo = (__hip_bfloat16*)alloc(128ull * 512 * 2);
  float* qhbuf = (float*)alloc(512ull * 2560 * 4);
  float* ctx = (float*)alloc(512ull * 512 * 4);
  float* hs = (float*)alloc(27ull * 512 * 512 * 4);  // slot 0 = zeros
  float* cstate = (float*)alloc(512ull * 512 * 4);

  dim3 tb(32, 8, 1);
  transpose_split<<<dim3(16, 16), tb, 0, stream>>>(Wi, 512, 512, Wi, 512, 512, WiT_hi, WiT_lo);
  transpose_split<<<dim3(80, 16), tb, 0, stream>>>(Wh, 512, 512, lstm_rec, 2048, 2560, W2T_hi, W2T_lo);
  transpose_split<<<dim3(64, 16), tb, 0, stream>>>(lstm_kernel, 2048, 2048, lstm_kernel, 2048, 2048, K1T_hi, K1T_lo);
  transpose_split<<<dim3(4, 16), tb, 0, stream>>>(Wgen, 96, 96, Wgen, 96, 96, WgT_hi, WgT_lo);

  hipMemsetAsync(hs, 0, (size_t)512 * 512 * 4, stream);
  hipMemsetAsync(cstate, 0, (size_t)512 * 512 * 4, stream);

  // Hproj (bf16 out) + bf16 batch_H side copy. M=32768, N=512, XCD-swizzled.
  gemm_split<2><<<dim3(8, 256), 256, 0, stream>>>(batch_H, WiT_hi, WiT_lo,
                                                  nullptr, 0, nullptr, Hp16, bH16);

  for (int s = 0; s < NSTEP; ++s) {
    const float* hptr = hs + (size_t)s * (NB * NH);
    // q | hrec = h @ [Wh | lstm_rec] : M=512, N=2560
    gemm_split<0><<<dim3(40, 4), 256, 0, stream>>>(hptr, W2T_hi, W2T_lo,
                                                   qhbuf, 2560, nullptr, nullptr, nullptr);
    attn_kernel<<<dim3(NB), 512, 0, stream>>>(qhbuf, bh, Ws, Hp16, bH16, ctx);
    // z = ctx @ lstm_kernel[:512] fused with LSTM pointwise
    gemm3_lstm<<<dim3(16, 8), 256, 0, stream>>>(ctx, K1T_hi, K1T_lo, qhbuf,
                                                lstm_bias, lstm_kernel, text, s, cstate, hs);
  }

  // probs = hs @ Wgen + bgen : M=13312, N=128 (96 valid)
  gemm_split<1><<<dim3(2, 104), 256, 0, stream>>>(hs + (size_t)NB * NH, WgT_hi, WgT_lo,
                                                  out, NCLS, bgen, nullptr, nullptr);
}